// Round 2
// baseline (1859.466 us; speedup 1.0000x reference)
//
#include <hip/hip_runtime.h>

// TreeRecurrentTagger: B=32, N=1023 nodes (complete heap), HID=128, NCLS=2.
// 3 stream-ordered kernels: subtree up-sweep (levels 8..4), middle (levels
// 3..0 up, g_down, down 0..3, classify 0..14), subtree down-sweep (4..8) +
// classify. Weights in per-thread registers, activations in LDS, fp32 VALU.
//
// R1: kB_mid rewritten (512 thr, phased register loads) — R0's kB hit the
// 256-VGPR cap and spilled ~66 MB/dispatch of scratch (WRITE_SIZE), 367 µs.

constexpr int NNODES = 1023;
constexpr int HB = 128;   // HID

// ---------- up-sweep level, 2-way k-split (kernel A) ----------
// 256 threads: i = t&127 (output row), half = t>>7 (k-half of 256-wide ctx).
template<int NN>
__device__ __forceinline__ void up_level(float* __restrict__ heap,
                                         float* __restrict__ red,
                                         const float4 (&w)[32],
                                         float bci, int i, int half) {
  constexpr int base = NN - 1, cb = 2 * NN - 1;
  float acc[NN];
#pragma unroll
  for (int j = 0; j < NN; ++j) acc[j] = 0.f;
  const float* ctx0 = heap + cb * HB + half * HB;
#pragma unroll
  for (int k4 = 0; k4 < 32; ++k4) {
    const float4 wv = w[k4];
#pragma unroll
    for (int j = 0; j < NN; ++j) {
      const float4 c = *(const float4*)(ctx0 + j * 2 * HB + k4 * 4);  // wave-uniform -> broadcast
      acc[j] = fmaf(wv.x, c.x, fmaf(wv.y, c.y, fmaf(wv.z, c.z, fmaf(wv.w, c.w, acc[j]))));
    }
  }
  if (half) {
#pragma unroll
    for (int j = 0; j < NN; ++j) red[j * HB + i] = acc[j];
  }
  __syncthreads();
  if (!half) {
#pragma unroll
    for (int j = 0; j < NN; ++j)
      heap[(base + j) * HB + i] = tanhf(acc[j] + red[j * HB + i] + bci);
  }
  __syncthreads();
}

// ---------- up-sweep level, 4-way k-split (kernel B, 512 thr) ----------
// i = t&127 (output row), q = t>>7 (quarter of the 256-wide ctx).
// Wc quarter-row = 16 float4 = 64 VGPRs.
template<int NN>
__device__ __forceinline__ void up_level4(float* __restrict__ heap,
                                          float* __restrict__ red,
                                          const float4 (&w)[16],
                                          float bci, int i, int q) {
  constexpr int base = NN - 1, cb = 2 * NN - 1;
  float acc[NN];
#pragma unroll
  for (int j = 0; j < NN; ++j) acc[j] = 0.f;
  const float* ctx0 = heap + cb * HB + q * 64;
#pragma unroll
  for (int k4 = 0; k4 < 16; ++k4) {
    const float4 wv = w[k4];
#pragma unroll
    for (int j = 0; j < NN; ++j) {
      const float4 c = *(const float4*)(ctx0 + j * 2 * HB + k4 * 4);
      acc[j] = fmaf(wv.x, c.x, fmaf(wv.y, c.y, fmaf(wv.z, c.z, fmaf(wv.w, c.w, acc[j]))));
    }
  }
  if (q) {
#pragma unroll
    for (int j = 0; j < NN; ++j) red[((q - 1) * NN + j) * HB + i] = acc[j];
  }
  __syncthreads();
  if (!q) {
#pragma unroll
    for (int j = 0; j < NN; ++j)
      heap[(base + j) * HB + i] =
          tanhf(acc[j] + red[j * HB + i] + red[(NN + j) * HB + i] +
                red[(2 * NN + j) * HB + i] + bci);
  }
  __syncthreads();
}

// ---------- down level, 2-way k-split (kernels B and C) ----------
// i = t&255 (output row), half = t>>8 (half 0: down-ctx, half 1: up-ctx).
// Wd half-row = 32 float4 = 128 VGPRs.
template<int NN>
__device__ __forceinline__ void down_level_C(float* __restrict__ db,
                                             const float* __restrict__ ub,
                                             float* __restrict__ red,
                                             const float4 (&w)[32],
                                             float bdi, int i, int half) {
  constexpr int base = NN - 1, cb = 2 * NN - 1;
  float acc[NN];
#pragma unroll
  for (int j = 0; j < NN; ++j) acc[j] = 0.f;
  const float* src = half ? (ub + base * HB) : (db + base * HB);
#pragma unroll
  for (int k4 = 0; k4 < 32; ++k4) {
    const float4 wv = w[k4];
#pragma unroll
    for (int j = 0; j < NN; ++j) {
      const float4 c = *(const float4*)(src + j * HB + k4 * 4);  // wave-uniform broadcast
      acc[j] = fmaf(wv.x, c.x, fmaf(wv.y, c.y, fmaf(wv.z, c.z, fmaf(wv.w, c.w, acc[j]))));
    }
  }
  if (half) {
#pragma unroll
    for (int j = 0; j < NN; ++j) red[j * 256 + i] = acc[j];
  }
  __syncthreads();
  if (!half) {
#pragma unroll
    for (int j = 0; j < NN; ++j) {
      const float v = tanhf(acc[j] + red[j * 256 + i] + bdi);
      if (i < 128) db[(cb + 2 * j) * HB + i] = v;
      else         db[(cb + 2 * j + 1) * HB + (i - 128)] = v;
    }
  }
  __syncthreads();
}

// ---------- classifier: softmax(sigmoid(Wcl @ [down, up] + bcl)) ----------
// rot breaks the stride-128 LDS conflict across lanes.
__device__ __forceinline__ void classify_node(const float* __restrict__ dn,
                                              const float* __restrict__ un,
                                              const float* __restrict__ wcl,
                                              const float* __restrict__ bcl,
                                              float* __restrict__ o, int rot) {
  float s0 = bcl[0], s1 = bcl[1];
#pragma unroll 4
  for (int kk = 0; kk < 128; ++kk) {
    const int k = (kk + rot) & 127;
    const float dv = dn[k];
    s0 = fmaf(dv, wcl[k], s0);
    s1 = fmaf(dv, wcl[256 + k], s1);
  }
  if (un) {
#pragma unroll 4
    for (int kk = 0; kk < 128; ++kk) {
      const int k = (kk + rot) & 127;
      const float uv = un[k];
      s0 = fmaf(uv, wcl[128 + k], s0);
      s1 = fmaf(uv, wcl[384 + k], s1);
    }
  }
  const float p0 = 1.f / (1.f + expf(-s0));
  const float p1 = 1.f / (1.f + expf(-s1));
  const float mx = fmaxf(p0, p1);
  const float e0 = expf(p0 - mx), e1 = expf(p1 - mx);
  const float inv = 1.f / (e0 + e1);
  o[0] = e0 * inv;
  o[1] = e1 * inv;
}

// ================= Kernel A: leaf gather + up levels 8..4 =================
// grid = 32*16 (batch, level-4 subtree); subtree root r = 15+s.
__global__ __launch_bounds__(256) void kA_up(const int* __restrict__ x,
                                             const int* __restrict__ cue,
                                             const float* __restrict__ emb,
                                             const float* __restrict__ Wc,
                                             const float* __restrict__ bc,
                                             float* __restrict__ hw) {
  __shared__ __align__(16) float heap[63 * HB];
  __shared__ __align__(16) float red[16 * HB];
  const int b = blockIdx.x >> 4, s = blockIdx.x & 15, r = 15 + s;
  const int t = threadIdx.x, i = t & 127, half = t >> 7;

  float4 w[32];
  const float4* wrow = (const float4*)(Wc + i * 256 + half * 128);
#pragma unroll
  for (int k = 0; k < 32; ++k) w[k] = wrow[k];
  const float bci = bc[i];

  // leaf features: [emb[x] (126) | one_hot(cue,2)]
  for (int idx = t; idx < 32 * HB; idx += 256) {
    const int j = idx >> 7, k = idx & 127;
    const int q = ((r + 1) << 5) - 1 + j;      // global leaf node (511..1022)
    float v;
    if (k < 126) v = emb[(long long)x[b * NNODES + q] * 126 + k];
    else         v = (cue[b * NNODES + q] == (k - 126)) ? 1.f : 0.f;
    heap[(31 + j) * HB + k] = v;
  }
  __syncthreads();

  up_level<16>(heap, red, w, bci, i, half);
  up_level<8>(heap, red, w, bci, i, half);
  up_level<4>(heap, red, w, bci, i, half);
  up_level<2>(heap, red, w, bci, i, half);
  up_level<1>(heap, red, w, bci, i, half);

  float* dst = hw + (size_t)(b * 16 + s) * 31 * HB;
  for (int idx = t; idx < 31 * HB; idx += 256) dst[idx] = heap[idx];
}

// ================= Kernel B: up 3..0, g_down, down 0..3, classify 0..14 =================
// 512 threads, one block per batch. Phased register loads keep peak VGPR low:
// phase U holds Wc quarter-rows (64 regs), phase D holds Wd half-rows (128).
__global__ __launch_bounds__(512) void kB_mid(const float* __restrict__ Wc,
                                              const float* __restrict__ bc,
                                              const float* __restrict__ Wg,
                                              const float* __restrict__ bg,
                                              const float* __restrict__ Wd,
                                              const float* __restrict__ bd,
                                              const float* __restrict__ Wcl,
                                              const float* __restrict__ bcl,
                                              const float* __restrict__ hw,
                                              float* __restrict__ dw,
                                              float* __restrict__ out) {
  __shared__ __align__(16) float ub[31 * HB];   // up h, nodes 0..30
  __shared__ __align__(16) float db[31 * HB];   // down, nodes 0..30
  __shared__ __align__(16) float red[16 * 256]; // 16 KB scratch for reductions
  __shared__ __align__(16) float wcl[512];
  const int b = blockIdx.x, t = threadIdx.x;

  // level-4 h (root of each subtree s) -> ub[15..30]
  for (int idx = t; idx < 16 * HB; idx += 512)
    ub[15 * HB + idx] = hw[(size_t)(b * 16 + (idx >> 7)) * 31 * HB + (idx & 127)];
  wcl[t] = Wcl[t];
  __syncthreads();

  // ---- up levels 3..0 + g_down (4-way k-split) ----
  {
    const int i = t & 127, q = t >> 7;
    float4 wu[16];
    const float4* wrow = (const float4*)(Wc + i * 256 + q * 64);
#pragma unroll
    for (int k = 0; k < 16; ++k) wu[k] = wrow[k];
    const float bci = bc[i];
    up_level4<8>(ub, red, wu, bci, i, q);
    up_level4<4>(ub, red, wu, bci, i, q);
    up_level4<2>(ub, red, wu, bci, i, q);
    up_level4<1>(ub, red, wu, bci, i, q);

    // g_down = sigmoid(Wg @ h_root + bg)
    float4 wg[8];
    const float4* wgrow = (const float4*)(Wg + i * 128 + q * 32);
#pragma unroll
    for (int k = 0; k < 8; ++k) wg[k] = wgrow[k];
    float acc = 0.f;
#pragma unroll
    for (int k4 = 0; k4 < 8; ++k4) {
      const float4 c = *(const float4*)(ub + q * 32 + k4 * 4);
      const float4 wv = wg[k4];
      acc = fmaf(wv.x, c.x, fmaf(wv.y, c.y, fmaf(wv.z, c.z, fmaf(wv.w, c.w, acc))));
    }
    if (q) red[(q - 1) * 128 + i] = acc;
    __syncthreads();
    if (!q)
      db[i] = 1.f / (1.f + expf(-(acc + red[i] + red[128 + i] + red[256 + i] + bg[i])));
    __syncthreads();
  }
  asm volatile("" ::: "memory");  // keep Wd loads from hoisting into phase U

  // ---- down levels 0..3 (Wd half-rows in regs, as kernel C) ----
  {
    const int i = t & 255, half = t >> 8;
    float4 w[32];
    const float4* wrow = (const float4*)(Wd + i * 256 + half * 128);
#pragma unroll
    for (int k = 0; k < 32; ++k) w[k] = wrow[k];
    const float bdi = bd[i];
    down_level_C<1>(db, ub, red, w, bdi, i, half);
    down_level_C<2>(db, ub, red, w, bdi, i, half);
    down_level_C<4>(db, ub, red, w, bdi, i, half);
    down_level_C<8>(db, ub, red, w, bdi, i, half);
  }

  // persist level-4 down (nodes 15..30) for kernel C
  for (int idx = t; idx < 16 * HB; idx += 512)
    dw[(size_t)(b * 16 + (idx >> 7)) * HB + (idx & 127)] = db[15 * HB + idx];

  // classify global nodes 0..14
  if (t < 15)
    classify_node(db + t * HB, ub + t * HB, wcl, bcl,
                  out + ((size_t)b * NNODES + t) * 2, t);
}

// ================= Kernel C: down levels 4..8 + classify 63 subtree nodes =================
__global__ __launch_bounds__(512) void kC_down(const float* __restrict__ Wd,
                                               const float* __restrict__ bd,
                                               const float* __restrict__ Wcl,
                                               const float* __restrict__ bcl,
                                               const float* __restrict__ hw,
                                               const float* __restrict__ dw,
                                               float* __restrict__ out) {
  __shared__ __align__(16) float ub[31 * HB];   // up h, local nodes 0..30
  __shared__ __align__(16) float db[63 * HB];   // down, local nodes 0..62
  __shared__ __align__(16) float red[16 * 256];
  __shared__ __align__(16) float wcl[512];
  const int b = blockIdx.x >> 4, s = blockIdx.x & 15, r = 15 + s;
  const int t = threadIdx.x, i = t & 255, half = t >> 8;

  float4 w[32];
  const float4* wrow = (const float4*)(Wd + i * 256 + half * 128);
#pragma unroll
  for (int k = 0; k < 32; ++k) w[k] = wrow[k];
  const float bdi = bd[i];

  const float* src = hw + (size_t)(b * 16 + s) * 31 * HB;
  for (int idx = t; idx < 31 * HB; idx += 512) ub[idx] = src[idx];
  if (t < HB) db[t] = dw[(size_t)(b * 16 + s) * HB + t];   // down at subtree root
  wcl[t] = Wcl[t];
  __syncthreads();

  down_level_C<1>(db, ub, red, w, bdi, i, half);
  down_level_C<2>(db, ub, red, w, bdi, i, half);
  down_level_C<4>(db, ub, red, w, bdi, i, half);
  down_level_C<8>(db, ub, red, w, bdi, i, half);
  down_level_C<16>(db, ub, red, w, bdi, i, half);

  // classify local heap nodes 0..62 (global levels 4..9); leaves have up = 0
  if (t < 63) {
    const int m = t;
    const int lvl = 31 - __clz(m + 1);
    const int j = (m + 1) - (1 << lvl);
    const int g = ((r + 1) << lvl) - 1 + j;
    classify_node(db + m * HB, (m < 31) ? (ub + m * HB) : nullptr, wcl, bcl,
                  out + ((size_t)b * NNODES + g) * 2, m);
  }
}

extern "C" void kernel_launch(void* const* d_in, const int* in_sizes, int n_in,
                              void* d_out, int out_size, void* d_ws, size_t ws_size,
                              hipStream_t stream) {
  const int*   x   = (const int*)d_in[0];
  // d_in[1] word_index: identity leaf mapping (leaf j at node 511+j) -- unused
  const int*   cue = (const int*)d_in[2];
  // d_in[3] adj: encodes the same hardcoded heap tree -- unused
  const float* emb = (const float*)d_in[4];
  const float* Wc  = (const float*)d_in[5];
  const float* bc  = (const float*)d_in[6];
  const float* Wd  = (const float*)d_in[7];
  const float* bd  = (const float*)d_in[8];
  const float* Wg  = (const float*)d_in[9];
  const float* bg  = (const float*)d_in[10];
  const float* Wcl = (const float*)d_in[11];
  const float* bcl = (const float*)d_in[12];
  float* out = (float*)d_out;

  float* hw = (float*)d_ws;                       // [B][16][31][128] up h
  float* dw = hw + (size_t)32 * 16 * 31 * 128;    // [B][16][128] level-4 down

  hipLaunchKernelGGL(kA_up,   dim3(512), dim3(256), 0, stream, x, cue, emb, Wc, bc, hw);
  hipLaunchKernelGGL(kB_mid,  dim3(32),  dim3(512), 0, stream,
                     Wc, bc, Wg, bg, Wd, bd, Wcl, bcl, hw, dw, out);
  hipLaunchKernelGGL(kC_down, dim3(512), dim3(512), 0, stream,
                     Wd, bd, Wcl, bcl, hw, dw, out);
}

// Round 3
// 1852.895 us; speedup vs baseline: 1.0035x; 1.0035x over previous
//
#include <hip/hip_runtime.h>

// TreeRecurrentTagger: B=32, N=1023 nodes (complete heap), HID=128, NCLS=2.
// 3 stream-ordered kernels: subtree up-sweep (levels 8..4), middle (levels
// 3..0 up, g_down, down 0..3, classify 0..14), subtree down-sweep (4..8) +
// classify. Weights in per-thread registers, activations in LDS, fp32 VALU.
//
// R1: kB_mid rewritten (512 thr, phased register loads) — R0's kB hit the
//     256-VGPR cap and spilled ~66 MB/dispatch of scratch.
// R2: explicit __launch_bounds__(N, 2) on ALL kernels. R1's co-compilation
//     flipped the allocator's occupancy heuristic on (unchanged!) kC_down to
//     a 128-VGPR target -> 2.1 GB/dispatch spill, 1389 µs. (N,2) pins the
//     budget at 256 VGPR/thread (2 waves/SIMD), which fits the 128 weight
//     regs + acc + addressing (~190) spill-free.

constexpr int NNODES = 1023;
constexpr int HB = 128;   // HID

// ---------- up-sweep level, 2-way k-split (kernel A) ----------
// 256 threads: i = t&127 (output row), half = t>>7 (k-half of 256-wide ctx).
template<int NN>
__device__ __forceinline__ void up_level(float* __restrict__ heap,
                                         float* __restrict__ red,
                                         const float4 (&w)[32],
                                         float bci, int i, int half) {
  constexpr int base = NN - 1, cb = 2 * NN - 1;
  float acc[NN];
#pragma unroll
  for (int j = 0; j < NN; ++j) acc[j] = 0.f;
  const float* ctx0 = heap + cb * HB + half * HB;
#pragma unroll
  for (int k4 = 0; k4 < 32; ++k4) {
    const float4 wv = w[k4];
#pragma unroll
    for (int j = 0; j < NN; ++j) {
      const float4 c = *(const float4*)(ctx0 + j * 2 * HB + k4 * 4);  // wave-uniform -> broadcast
      acc[j] = fmaf(wv.x, c.x, fmaf(wv.y, c.y, fmaf(wv.z, c.z, fmaf(wv.w, c.w, acc[j]))));
    }
  }
  if (half) {
#pragma unroll
    for (int j = 0; j < NN; ++j) red[j * HB + i] = acc[j];
  }
  __syncthreads();
  if (!half) {
#pragma unroll
    for (int j = 0; j < NN; ++j)
      heap[(base + j) * HB + i] = tanhf(acc[j] + red[j * HB + i] + bci);
  }
  __syncthreads();
}

// ---------- up-sweep level, 4-way k-split (kernel B, 512 thr) ----------
// i = t&127 (output row), q = t>>7 (quarter of the 256-wide ctx).
// Wc quarter-row = 16 float4 = 64 VGPRs.
template<int NN>
__device__ __forceinline__ void up_level4(float* __restrict__ heap,
                                          float* __restrict__ red,
                                          const float4 (&w)[16],
                                          float bci, int i, int q) {
  constexpr int base = NN - 1, cb = 2 * NN - 1;
  float acc[NN];
#pragma unroll
  for (int j = 0; j < NN; ++j) acc[j] = 0.f;
  const float* ctx0 = heap + cb * HB + q * 64;
#pragma unroll
  for (int k4 = 0; k4 < 16; ++k4) {
    const float4 wv = w[k4];
#pragma unroll
    for (int j = 0; j < NN; ++j) {
      const float4 c = *(const float4*)(ctx0 + j * 2 * HB + k4 * 4);
      acc[j] = fmaf(wv.x, c.x, fmaf(wv.y, c.y, fmaf(wv.z, c.z, fmaf(wv.w, c.w, acc[j]))));
    }
  }
  if (q) {
#pragma unroll
    for (int j = 0; j < NN; ++j) red[((q - 1) * NN + j) * HB + i] = acc[j];
  }
  __syncthreads();
  if (!q) {
#pragma unroll
    for (int j = 0; j < NN; ++j)
      heap[(base + j) * HB + i] =
          tanhf(acc[j] + red[j * HB + i] + red[(NN + j) * HB + i] +
                red[(2 * NN + j) * HB + i] + bci);
  }
  __syncthreads();
}

// ---------- down level, 2-way k-split (kernels B and C) ----------
// i = t&255 (output row), half = t>>8 (half 0: down-ctx, half 1: up-ctx).
// Wd half-row = 32 float4 = 128 VGPRs.
template<int NN>
__device__ __forceinline__ void down_level_C(float* __restrict__ db,
                                             const float* __restrict__ ub,
                                             float* __restrict__ red,
                                             const float4 (&w)[32],
                                             float bdi, int i, int half) {
  constexpr int base = NN - 1, cb = 2 * NN - 1;
  float acc[NN];
#pragma unroll
  for (int j = 0; j < NN; ++j) acc[j] = 0.f;
  const float* src = half ? (ub + base * HB) : (db + base * HB);
#pragma unroll
  for (int k4 = 0; k4 < 32; ++k4) {
    const float4 wv = w[k4];
#pragma unroll
    for (int j = 0; j < NN; ++j) {
      const float4 c = *(const float4*)(src + j * HB + k4 * 4);  // wave-uniform broadcast
      acc[j] = fmaf(wv.x, c.x, fmaf(wv.y, c.y, fmaf(wv.z, c.z, fmaf(wv.w, c.w, acc[j]))));
    }
  }
  if (half) {
#pragma unroll
    for (int j = 0; j < NN; ++j) red[j * 256 + i] = acc[j];
  }
  __syncthreads();
  if (!half) {
#pragma unroll
    for (int j = 0; j < NN; ++j) {
      const float v = tanhf(acc[j] + red[j * 256 + i] + bdi);
      if (i < 128) db[(cb + 2 * j) * HB + i] = v;
      else         db[(cb + 2 * j + 1) * HB + (i - 128)] = v;
    }
  }
  __syncthreads();
}

// ---------- classifier: softmax(sigmoid(Wcl @ [down, up] + bcl)) ----------
// rot breaks the stride-128 LDS conflict across lanes.
__device__ __forceinline__ void classify_node(const float* __restrict__ dn,
                                              const float* __restrict__ un,
                                              const float* __restrict__ wcl,
                                              const float* __restrict__ bcl,
                                              float* __restrict__ o, int rot) {
  float s0 = bcl[0], s1 = bcl[1];
#pragma unroll 4
  for (int kk = 0; kk < 128; ++kk) {
    const int k = (kk + rot) & 127;
    const float dv = dn[k];
    s0 = fmaf(dv, wcl[k], s0);
    s1 = fmaf(dv, wcl[256 + k], s1);
  }
  if (un) {
#pragma unroll 4
    for (int kk = 0; kk < 128; ++kk) {
      const int k = (kk + rot) & 127;
      const float uv = un[k];
      s0 = fmaf(uv, wcl[128 + k], s0);
      s1 = fmaf(uv, wcl[384 + k], s1);
    }
  }
  const float p0 = 1.f / (1.f + expf(-s0));
  const float p1 = 1.f / (1.f + expf(-s1));
  const float mx = fmaxf(p0, p1);
  const float e0 = expf(p0 - mx), e1 = expf(p1 - mx);
  const float inv = 1.f / (e0 + e1);
  o[0] = e0 * inv;
  o[1] = e1 * inv;
}

// ================= Kernel A: leaf gather + up levels 8..4 =================
// grid = 32*16 (batch, level-4 subtree); subtree root r = 15+s.
__global__ __launch_bounds__(256, 2) void kA_up(const int* __restrict__ x,
                                                const int* __restrict__ cue,
                                                const float* __restrict__ emb,
                                                const float* __restrict__ Wc,
                                                const float* __restrict__ bc,
                                                float* __restrict__ hw) {
  __shared__ __align__(16) float heap[63 * HB];
  __shared__ __align__(16) float red[16 * HB];
  const int b = blockIdx.x >> 4, s = blockIdx.x & 15, r = 15 + s;
  const int t = threadIdx.x, i = t & 127, half = t >> 7;

  float4 w[32];
  const float4* wrow = (const float4*)(Wc + i * 256 + half * 128);
#pragma unroll
  for (int k = 0; k < 32; ++k) w[k] = wrow[k];
  const float bci = bc[i];

  // leaf features: [emb[x] (126) | one_hot(cue,2)]
  for (int idx = t; idx < 32 * HB; idx += 256) {
    const int j = idx >> 7, k = idx & 127;
    const int q = ((r + 1) << 5) - 1 + j;      // global leaf node (511..1022)
    float v;
    if (k < 126) v = emb[(long long)x[b * NNODES + q] * 126 + k];
    else         v = (cue[b * NNODES + q] == (k - 126)) ? 1.f : 0.f;
    heap[(31 + j) * HB + k] = v;
  }
  __syncthreads();

  up_level<16>(heap, red, w, bci, i, half);
  up_level<8>(heap, red, w, bci, i, half);
  up_level<4>(heap, red, w, bci, i, half);
  up_level<2>(heap, red, w, bci, i, half);
  up_level<1>(heap, red, w, bci, i, half);

  float* dst = hw + (size_t)(b * 16 + s) * 31 * HB;
  for (int idx = t; idx < 31 * HB; idx += 256) dst[idx] = heap[idx];
}

// ================= Kernel B: up 3..0, g_down, down 0..3, classify 0..14 =================
// 512 threads, one block per batch. Phased register loads keep peak VGPR low:
// phase U holds Wc quarter-rows (64 regs), phase D holds Wd half-rows (128).
__global__ __launch_bounds__(512, 2) void kB_mid(const float* __restrict__ Wc,
                                                 const float* __restrict__ bc,
                                                 const float* __restrict__ Wg,
                                                 const float* __restrict__ bg,
                                                 const float* __restrict__ Wd,
                                                 const float* __restrict__ bd,
                                                 const float* __restrict__ Wcl,
                                                 const float* __restrict__ bcl,
                                                 const float* __restrict__ hw,
                                                 float* __restrict__ dw,
                                                 float* __restrict__ out) {
  __shared__ __align__(16) float ub[31 * HB];   // up h, nodes 0..30
  __shared__ __align__(16) float db[31 * HB];   // down, nodes 0..30
  __shared__ __align__(16) float red[16 * 256]; // 16 KB scratch for reductions
  __shared__ __align__(16) float wcl[512];
  const int b = blockIdx.x, t = threadIdx.x;

  // level-4 h (root of each subtree s) -> ub[15..30]
  for (int idx = t; idx < 16 * HB; idx += 512)
    ub[15 * HB + idx] = hw[(size_t)(b * 16 + (idx >> 7)) * 31 * HB + (idx & 127)];
  wcl[t] = Wcl[t];
  __syncthreads();

  // ---- up levels 3..0 + g_down (4-way k-split) ----
  {
    const int i = t & 127, q = t >> 7;
    float4 wu[16];
    const float4* wrow = (const float4*)(Wc + i * 256 + q * 64);
#pragma unroll
    for (int k = 0; k < 16; ++k) wu[k] = wrow[k];
    const float bci = bc[i];
    up_level4<8>(ub, red, wu, bci, i, q);
    up_level4<4>(ub, red, wu, bci, i, q);
    up_level4<2>(ub, red, wu, bci, i, q);
    up_level4<1>(ub, red, wu, bci, i, q);

    // g_down = sigmoid(Wg @ h_root + bg)
    float4 wg[8];
    const float4* wgrow = (const float4*)(Wg + i * 128 + q * 32);
#pragma unroll
    for (int k = 0; k < 8; ++k) wg[k] = wgrow[k];
    float acc = 0.f;
#pragma unroll
    for (int k4 = 0; k4 < 8; ++k4) {
      const float4 c = *(const float4*)(ub + q * 32 + k4 * 4);
      const float4 wv = wg[k4];
      acc = fmaf(wv.x, c.x, fmaf(wv.y, c.y, fmaf(wv.z, c.z, fmaf(wv.w, c.w, acc))));
    }
    if (q) red[(q - 1) * 128 + i] = acc;
    __syncthreads();
    if (!q)
      db[i] = 1.f / (1.f + expf(-(acc + red[i] + red[128 + i] + red[256 + i] + bg[i])));
    __syncthreads();
  }
  asm volatile("" ::: "memory");  // keep Wd loads from hoisting into phase U

  // ---- down levels 0..3 (Wd half-rows in regs, as kernel C) ----
  {
    const int i = t & 255, half = t >> 8;
    float4 w[32];
    const float4* wrow = (const float4*)(Wd + i * 256 + half * 128);
#pragma unroll
    for (int k = 0; k < 32; ++k) w[k] = wrow[k];
    const float bdi = bd[i];
    down_level_C<1>(db, ub, red, w, bdi, i, half);
    down_level_C<2>(db, ub, red, w, bdi, i, half);
    down_level_C<4>(db, ub, red, w, bdi, i, half);
    down_level_C<8>(db, ub, red, w, bdi, i, half);
  }

  // persist level-4 down (nodes 15..30) for kernel C
  for (int idx = t; idx < 16 * HB; idx += 512)
    dw[(size_t)(b * 16 + (idx >> 7)) * HB + (idx & 127)] = db[15 * HB + idx];

  // classify global nodes 0..14
  if (t < 15)
    classify_node(db + t * HB, ub + t * HB, wcl, bcl,
                  out + ((size_t)b * NNODES + t) * 2, t);
}

// ================= Kernel C: down levels 4..8 + classify 63 subtree nodes =================
__global__ __launch_bounds__(512, 2) void kC_down(const float* __restrict__ Wd,
                                                  const float* __restrict__ bd,
                                                  const float* __restrict__ Wcl,
                                                  const float* __restrict__ bcl,
                                                  const float* __restrict__ hw,
                                                  const float* __restrict__ dw,
                                                  float* __restrict__ out) {
  __shared__ __align__(16) float ub[31 * HB];   // up h, local nodes 0..30
  __shared__ __align__(16) float db[63 * HB];   // down, local nodes 0..62
  __shared__ __align__(16) float red[16 * 256];
  __shared__ __align__(16) float wcl[512];
  const int b = blockIdx.x >> 4, s = blockIdx.x & 15, r = 15 + s;
  const int t = threadIdx.x, i = t & 255, half = t >> 8;

  float4 w[32];
  const float4* wrow = (const float4*)(Wd + i * 256 + half * 128);
#pragma unroll
  for (int k = 0; k < 32; ++k) w[k] = wrow[k];
  const float bdi = bd[i];

  const float* src = hw + (size_t)(b * 16 + s) * 31 * HB;
  for (int idx = t; idx < 31 * HB; idx += 512) ub[idx] = src[idx];
  if (t < HB) db[t] = dw[(size_t)(b * 16 + s) * HB + t];   // down at subtree root
  wcl[t] = Wcl[t];
  __syncthreads();

  down_level_C<1>(db, ub, red, w, bdi, i, half);
  down_level_C<2>(db, ub, red, w, bdi, i, half);
  down_level_C<4>(db, ub, red, w, bdi, i, half);
  down_level_C<8>(db, ub, red, w, bdi, i, half);
  down_level_C<16>(db, ub, red, w, bdi, i, half);

  // classify local heap nodes 0..62 (global levels 4..9); leaves have up = 0
  if (t < 63) {
    const int m = t;
    const int lvl = 31 - __clz(m + 1);
    const int j = (m + 1) - (1 << lvl);
    const int g = ((r + 1) << lvl) - 1 + j;
    classify_node(db + m * HB, (m < 31) ? (ub + m * HB) : nullptr, wcl, bcl,
                  out + ((size_t)b * NNODES + g) * 2, m);
  }
}

extern "C" void kernel_launch(void* const* d_in, const int* in_sizes, int n_in,
                              void* d_out, int out_size, void* d_ws, size_t ws_size,
                              hipStream_t stream) {
  const int*   x   = (const int*)d_in[0];
  // d_in[1] word_index: identity leaf mapping (leaf j at node 511+j) -- unused
  const int*   cue = (const int*)d_in[2];
  // d_in[3] adj: encodes the same hardcoded heap tree -- unused
  const float* emb = (const float*)d_in[4];
  const float* Wc  = (const float*)d_in[5];
  const float* bc  = (const float*)d_in[6];
  const float* Wd  = (const float*)d_in[7];
  const float* bd  = (const float*)d_in[8];
  const float* Wg  = (const float*)d_in[9];
  const float* bg  = (const float*)d_in[10];
  const float* Wcl = (const float*)d_in[11];
  const float* bcl = (const float*)d_in[12];
  float* out = (float*)d_out;

  float* hw = (float*)d_ws;                       // [B][16][31][128] up h
  float* dw = hw + (size_t)32 * 16 * 31 * 128;    // [B][16][128] level-4 down

  hipLaunchKernelGGL(kA_up,   dim3(512), dim3(256), 0, stream, x, cue, emb, Wc, bc, hw);
  hipLaunchKernelGGL(kB_mid,  dim3(32),  dim3(512), 0, stream,
                     Wc, bc, Wg, bg, Wd, bd, Wcl, bcl, hw, dw, out);
  hipLaunchKernelGGL(kC_down, dim3(512), dim3(512), 0, stream,
                     Wd, bd, Wcl, bcl, hw, dw, out);
}

// Round 4
// 142.592 us; speedup vs baseline: 13.0404x; 12.9944x over previous
//
#include <hip/hip_runtime.h>

// TreeRecurrentTagger: B=32, N=1023 nodes (complete heap), HID=128, NCLS=2.
// 3 stream-ordered kernels: subtree up-sweep (levels 8..4), middle (levels
// 3..0 up, g_down, down 0..3, classify 0..14), subtree down-sweep (4..8) +
// classify. Weights in per-thread registers, activations in LDS, fp32 VALU.
//
// R1: kB phased loads (R0 kB spilled at the 256-VGPR cap, 66 MB scratch).
// R2: __launch_bounds__(N,2) — NO effect: RA still capped kC at 128 VGPR and
//     spilled 2.1 GB/dispatch. The RA targets an occupancy (LDS-derived) and
//     spills to meet it; min-waves only raises the cap, not the target.
// R3: fit UNDER the cap instead of fighting it. 4-way k-split -> weight
//     slice = 16 float4 = 64 VGPR, acc chunk CH=4, peak ~105 VGPR. Down
//     levels use 1024-thr blocks (256 rows x 4 quarters). LDS oversized so
//     kB/kC sit at 1 block/CU (>80 KB) and kA at 2 blocks/CU (~60 KB),
//     pinning the RA occupancy target at 4 waves/SIMD (128-reg cap).

constexpr int NNODES = 1023;
constexpr int HB = 128;   // HID

// ---------- up level: out = tanh(Wc @ [h_left, h_right] + bc) ----------
// NQ-way k-split of the 256-wide child ctx. i = output row (0..127),
// q = k-slice (0..NQ-1). CH parents per chunk keep acc tiny.
// Children of local node (base+p) sit at (cb+2p),(cb+2p+1): 256 contiguous.
template<int NP, int NQ>
__device__ __forceinline__ void up4(float* __restrict__ heap,
                                    float* __restrict__ red,
                                    const float4 (&w)[64 / NQ],
                                    float bci, int i, int q) {
  constexpr int base = NP - 1, cb = 2 * NP - 1;
  constexpr int CH = (NP < 4) ? NP : 4;
  constexpr int K4 = 64 / NQ;
#pragma unroll
  for (int c = 0; c < NP; c += CH) {
    float acc[CH];
#pragma unroll
    for (int j = 0; j < CH; ++j) acc[j] = 0.f;
    const float* ctx0 = heap + (cb + 2 * c) * HB + q * (256 / NQ);
#pragma unroll
    for (int k4 = 0; k4 < K4; ++k4) {
      const float4 wv = w[k4];
#pragma unroll
      for (int j = 0; j < CH; ++j) {
        const float4 cc = *(const float4*)(ctx0 + j * 2 * HB + k4 * 4);  // wave-uniform -> LDS broadcast
        acc[j] = fmaf(wv.x, cc.x, fmaf(wv.y, cc.y, fmaf(wv.z, cc.z, fmaf(wv.w, cc.w, acc[j]))));
      }
    }
    if (q) {
#pragma unroll
      for (int j = 0; j < CH; ++j) red[((q - 1) * CH + j) * HB + i] = acc[j];
    }
    __syncthreads();
    if (!q) {
#pragma unroll
      for (int j = 0; j < CH; ++j) {
        float s = acc[j] + bci;
#pragma unroll
        for (int m = 0; m < NQ - 1; ++m) s += red[(m * CH + j) * HB + i];
        heap[(base + c + j) * HB + i] = tanhf(s);
      }
    }
    __syncthreads();
  }
}

// ---------- down level: ch = tanh(Wd @ [down_p, up_p] + bd) ----------
// 1024 threads: i = t&255 (output row), q = t>>8 (k-quarter). Quarters 0,1
// read the down part of ctx, 2,3 the up part. Row i<128 -> left child,
// i>=128 -> right child.
template<int NP>
__device__ __forceinline__ void down4(float* __restrict__ db,
                                      const float* __restrict__ ub,
                                      float* __restrict__ red,
                                      const float4 (&w)[16],
                                      float bdi, int i, int q) {
  constexpr int base = NP - 1, cb = 2 * NP - 1;
  constexpr int CH = (NP < 4) ? NP : 4;
#pragma unroll
  for (int c = 0; c < NP; c += CH) {
    float acc[CH];
#pragma unroll
    for (int j = 0; j < CH; ++j) acc[j] = 0.f;
    const float* src = (q < 2 ? db : ub) + (base + c) * HB + (q & 1) * 64;
#pragma unroll
    for (int k4 = 0; k4 < 16; ++k4) {
      const float4 wv = w[k4];
#pragma unroll
      for (int j = 0; j < CH; ++j) {
        const float4 cc = *(const float4*)(src + j * HB + k4 * 4);  // wave-uniform -> LDS broadcast
        acc[j] = fmaf(wv.x, cc.x, fmaf(wv.y, cc.y, fmaf(wv.z, cc.z, fmaf(wv.w, cc.w, acc[j]))));
      }
    }
    if (q) {
#pragma unroll
      for (int j = 0; j < CH; ++j) red[((q - 1) * CH + j) * 256 + i] = acc[j];
    }
    __syncthreads();
    if (!q) {
#pragma unroll
      for (int j = 0; j < CH; ++j) {
        const float v = tanhf(acc[j] + red[j * 256 + i] + red[(CH + j) * 256 + i] +
                              red[(2 * CH + j) * 256 + i] + bdi);
        db[(cb + 2 * (c + j) + (i >> 7)) * HB + (i & 127)] = v;
      }
    }
    __syncthreads();
  }
}

// ---------- classifier: softmax(sigmoid(Wcl @ [down, up] + bcl)) ----------
// rot staggers banks across the per-node rows.
__device__ __forceinline__ void classify_node(const float* __restrict__ dn,
                                              const float* __restrict__ un,
                                              const float* __restrict__ wcl,
                                              const float* __restrict__ bcl,
                                              float* __restrict__ o, int rot) {
  float s0 = bcl[0], s1 = bcl[1];
#pragma unroll 4
  for (int kk = 0; kk < 128; ++kk) {
    const int k = (kk + rot) & 127;
    const float dv = dn[k];
    s0 = fmaf(dv, wcl[k], s0);
    s1 = fmaf(dv, wcl[256 + k], s1);
  }
  if (un) {
#pragma unroll 4
    for (int kk = 0; kk < 128; ++kk) {
      const int k = (kk + rot) & 127;
      const float uv = un[k];
      s0 = fmaf(uv, wcl[128 + k], s0);
      s1 = fmaf(uv, wcl[384 + k], s1);
    }
  }
  const float p0 = 1.f / (1.f + expf(-s0));
  const float p1 = 1.f / (1.f + expf(-s1));
  const float mx = fmaxf(p0, p1);
  const float e0 = expf(p0 - mx), e1 = expf(p1 - mx);
  const float inv = 1.f / (e0 + e1);
  o[0] = e0 * inv;
  o[1] = e1 * inv;
}

// ================= Kernel A: leaf gather + up levels 8..4 =================
// grid = 32*16 (batch, level-4 subtree); subtree root r = 15+s.
// 512 thr: i = t&127, q = t>>7 (4-way k-split). ~60 KB LDS -> 2 blocks/CU.
__global__ __launch_bounds__(512, 4) void kA_up(const int* __restrict__ x,
                                                const int* __restrict__ cue,
                                                const float* __restrict__ emb,
                                                const float* __restrict__ Wc,
                                                const float* __restrict__ bc,
                                                float* __restrict__ hw) {
  __shared__ __align__(16) float heap[63 * HB];
  __shared__ __align__(16) float red[7296];   // 1536 used; oversized to pin occupancy
  const int b = blockIdx.x >> 4, s = blockIdx.x & 15, r = 15 + s;
  const int t = threadIdx.x, i = t & 127, q = t >> 7;

  float4 w[16];
  const float4* wrow = (const float4*)(Wc + i * 256 + q * 64);
#pragma unroll
  for (int k = 0; k < 16; ++k) w[k] = wrow[k];
  const float bci = bc[i];

  // leaf features: [emb[x] (126) | one_hot(cue,2)]
  for (int idx = t; idx < 32 * HB; idx += 512) {
    const int j = idx >> 7, k = idx & 127;
    const int g = ((r + 1) << 5) - 1 + j;      // global leaf node (511..1022)
    float v;
    if (k < 126) v = emb[(long long)x[b * NNODES + g] * 126 + k];
    else         v = (cue[b * NNODES + g] == (k - 126)) ? 1.f : 0.f;
    heap[(31 + j) * HB + k] = v;
  }
  __syncthreads();

  up4<16, 4>(heap, red, w, bci, i, q);
  up4<8, 4>(heap, red, w, bci, i, q);
  up4<4, 4>(heap, red, w, bci, i, q);
  up4<2, 4>(heap, red, w, bci, i, q);
  up4<1, 4>(heap, red, w, bci, i, q);

  float* dst = hw + (size_t)(b * 16 + s) * 31 * HB;
  for (int idx = t; idx < 31 * HB; idx += 512) dst[idx] = heap[idx];
}

// ================= Kernel B: up 3..0, g_down, down 0..3, classify 0..14 =================
// 1024 thr, one block per batch. Up phase: 8-way k-split (all threads busy).
// Down phase: 4-way. >80 KB LDS -> 1 block/CU -> RA reg cap 128.
__global__ __launch_bounds__(1024, 4) void kB_mid(const float* __restrict__ Wc,
                                                  const float* __restrict__ bc,
                                                  const float* __restrict__ Wg,
                                                  const float* __restrict__ bg,
                                                  const float* __restrict__ Wd,
                                                  const float* __restrict__ bd,
                                                  const float* __restrict__ Wcl,
                                                  const float* __restrict__ bcl,
                                                  const float* __restrict__ hw,
                                                  float* __restrict__ dw,
                                                  float* __restrict__ out) {
  __shared__ __align__(16) float ub[31 * HB];   // up h, nodes 0..30
  __shared__ __align__(16) float db[31 * HB];   // down, nodes 0..30
  __shared__ __align__(16) float red[12084];    // 3584 used; oversized to pin occupancy
  __shared__ __align__(16) float wcl[512];
  const int b = blockIdx.x, t = threadIdx.x;

  // level-4 h (root of each subtree s) -> ub[15..30]
  for (int idx = t; idx < 16 * HB; idx += 1024)
    ub[15 * HB + idx] = hw[(size_t)(b * 16 + (idx >> 7)) * 31 * HB + (idx & 127)];
  if (t < 512) wcl[t] = Wcl[t];
  __syncthreads();

  // ---- up levels 3..0 (8-way k-split) + g_down ----
  {
    const int i = t & 127, q = t >> 7;           // q in 0..7
    float4 wu[8];
    const float4* wrow = (const float4*)(Wc + i * 256 + q * 32);
#pragma unroll
    for (int k = 0; k < 8; ++k) wu[k] = wrow[k];
    const float bci = bc[i];
    up4<8, 8>(ub, red, wu, bci, i, q);
    up4<4, 8>(ub, red, wu, bci, i, q);
    up4<2, 8>(ub, red, wu, bci, i, q);
    up4<1, 8>(ub, red, wu, bci, i, q);

    // g_down = sigmoid(Wg @ h_root + bg), 8-way split of 128-wide ctx
    float4 wg[4];
    const float4* wgrow = (const float4*)(Wg + i * 128 + q * 16);
#pragma unroll
    for (int k = 0; k < 4; ++k) wg[k] = wgrow[k];
    float acc = 0.f;
#pragma unroll
    for (int k4 = 0; k4 < 4; ++k4) {
      const float4 cc = *(const float4*)(ub + q * 16 + k4 * 4);
      const float4 wv = wg[k4];
      acc = fmaf(wv.x, cc.x, fmaf(wv.y, cc.y, fmaf(wv.z, cc.z, fmaf(wv.w, cc.w, acc))));
    }
    if (q) red[(q - 1) * 128 + i] = acc;
    __syncthreads();
    if (!q) {
      float sum = acc + bg[i];
#pragma unroll
      for (int m = 0; m < 7; ++m) sum += red[m * 128 + i];
      db[i] = 1.f / (1.f + expf(-sum));
    }
    __syncthreads();
  }
  asm volatile("" ::: "memory");  // keep Wd loads from hoisting into the up phase

  // ---- down levels 0..3 (4-way k-split) ----
  {
    const int i = t & 255, q = t >> 8;           // q in 0..3
    float4 w[16];
    const float4* wrow = (const float4*)(Wd + i * 256 + q * 64);
#pragma unroll
    for (int k = 0; k < 16; ++k) w[k] = wrow[k];
    const float bdi = bd[i];
    down4<1>(db, ub, red, w, bdi, i, q);
    down4<2>(db, ub, red, w, bdi, i, q);
    down4<4>(db, ub, red, w, bdi, i, q);
    down4<8>(db, ub, red, w, bdi, i, q);
  }

  // persist level-4 down (nodes 15..30) for kernel C
  for (int idx = t; idx < 16 * HB; idx += 1024)
    dw[(size_t)(b * 16 + (idx >> 7)) * HB + (idx & 127)] = db[15 * HB + idx];

  // classify global nodes 0..14
  if (t < 15)
    classify_node(db + t * HB, ub + t * HB, wcl, bcl,
                  out + ((size_t)b * NNODES + t) * 2, t);
}

// ================= Kernel C: down levels 4..8 + classify 63 subtree nodes =================
// 1024 thr: i = t&255, q = t>>8 (4-way k-split). >80 KB LDS -> 1 block/CU.
__global__ __launch_bounds__(1024, 4) void kC_down(const float* __restrict__ Wd,
                                                   const float* __restrict__ bd,
                                                   const float* __restrict__ Wcl,
                                                   const float* __restrict__ bcl,
                                                   const float* __restrict__ hw,
                                                   const float* __restrict__ dw,
                                                   float* __restrict__ out) {
  __shared__ __align__(16) float ub[31 * HB];   // up h, local nodes 0..30
  __shared__ __align__(16) float db[63 * HB];   // down, local nodes 0..62
  __shared__ __align__(16) float red[7960];     // 3072 used; oversized to pin occupancy
  __shared__ __align__(16) float wcl[512];
  const int b = blockIdx.x >> 4, s = blockIdx.x & 15, r = 15 + s;
  const int t = threadIdx.x, i = t & 255, q = t >> 8;

  float4 w[16];
  const float4* wrow = (const float4*)(Wd + i * 256 + q * 64);
#pragma unroll
  for (int k = 0; k < 16; ++k) w[k] = wrow[k];
  const float bdi = bd[i];

  const float* src = hw + (size_t)(b * 16 + s) * 31 * HB;
  for (int idx = t; idx < 31 * HB; idx += 1024) ub[idx] = src[idx];
  if (t < HB) db[t] = dw[(size_t)(b * 16 + s) * HB + t];   // down at subtree root
  if (t < 512) wcl[t] = Wcl[t];
  __syncthreads();

  down4<1>(db, ub, red, w, bdi, i, q);
  down4<2>(db, ub, red, w, bdi, i, q);
  down4<4>(db, ub, red, w, bdi, i, q);
  down4<8>(db, ub, red, w, bdi, i, q);
  down4<16>(db, ub, red, w, bdi, i, q);

  // classify local heap nodes 0..62 (global levels 4..9); leaves have up = 0
  if (t < 63) {
    const int m = t;
    const int lvl = 31 - __clz(m + 1);
    const int j = (m + 1) - (1 << lvl);
    const int g = ((r + 1) << lvl) - 1 + j;
    classify_node(db + m * HB, (m < 31) ? (ub + m * HB) : nullptr, wcl, bcl,
                  out + ((size_t)b * NNODES + g) * 2, m);
  }
}

extern "C" void kernel_launch(void* const* d_in, const int* in_sizes, int n_in,
                              void* d_out, int out_size, void* d_ws, size_t ws_size,
                              hipStream_t stream) {
  const int*   x   = (const int*)d_in[0];
  // d_in[1] word_index: identity leaf mapping (leaf j at node 511+j) -- unused
  const int*   cue = (const int*)d_in[2];
  // d_in[3] adj: encodes the same hardcoded heap tree -- unused
  const float* emb = (const float*)d_in[4];
  const float* Wc  = (const float*)d_in[5];
  const float* bc  = (const float*)d_in[6];
  const float* Wd  = (const float*)d_in[7];
  const float* bd  = (const float*)d_in[8];
  const float* Wg  = (const float*)d_in[9];
  const float* bg  = (const float*)d_in[10];
  const float* Wcl = (const float*)d_in[11];
  const float* bcl = (const float*)d_in[12];
  float* out = (float*)d_out;

  float* hw = (float*)d_ws;                       // [B][16][31][128] up h
  float* dw = hw + (size_t)32 * 16 * 31 * 128;    // [B][16][128] level-4 down

  hipLaunchKernelGGL(kA_up,   dim3(512), dim3(512), 0, stream, x, cue, emb, Wc, bc, hw);
  hipLaunchKernelGGL(kB_mid,  dim3(32),  dim3(1024), 0, stream,
                     Wc, bc, Wg, bg, Wd, bd, Wcl, bcl, hw, dw, out);
  hipLaunchKernelGGL(kC_down, dim3(512), dim3(1024), 0, stream,
                     Wd, bd, Wcl, bcl, hw, dw, out);
}